// Round 1
// baseline (865.357 us; speedup 1.0000x reference)
//
#include <hip/hip_runtime.h>
#include <hip/hip_bf16.h>

typedef unsigned short u16;
typedef __attribute__((ext_vector_type(8))) short short8v;
typedef __attribute__((ext_vector_type(4))) float f32x4;

#define N_NODES 8192
#define IN_F    512
#define HID     256
#define OUT_F   512

static __device__ __forceinline__ u16 f2bf(float f) {
    union { float f; unsigned u; } v; v.f = f;
    unsigned u = v.u;
    // round-to-nearest-even
    unsigned r = (u + 0x7FFFu + ((u >> 16) & 1u)) >> 16;
    return (u16)r;
}

// ---------------- K1: rowsum(adj + I) -> r = rsqrt ----------------
__global__ __launch_bounds__(256) void k_rowsum(const float* __restrict__ adj,
                                                float* __restrict__ r) {
    const int row = blockIdx.x;
    const float* p = adj + (size_t)row * N_NODES;
    const int t = threadIdx.x;
    float s = 0.f;
#pragma unroll
    for (int it = 0; it < 8; ++it) {
        float4 v = *(const float4*)(p + it * 1024 + t * 4);
        s += (v.x + v.y) + (v.z + v.w);
    }
#pragma unroll
    for (int off = 32; off > 0; off >>= 1) s += __shfl_down(s, off, 64);
    __shared__ float red[4];
    const int lane = t & 63, wid = t >> 6;
    if (lane == 0) red[wid] = s;
    __syncthreads();
    if (t == 0) {
        float tot = red[0] + red[1] + red[2] + red[3] + 1.0f;  // +1 from identity
        r[row] = (tot > 0.f) ? rsqrtf(tot) : 0.f;
    }
}

// ---------------- K2a: h1[8192,256] (bf16) = x @ W1^T + b1 ----------------
__global__ __launch_bounds__(256) void k_fc1(const float* __restrict__ x,
                                             const float* __restrict__ W1,
                                             const float* __restrict__ bias1,
                                             u16* __restrict__ h1) {
    const int m0 = blockIdx.x * 64;
    const int lane = threadIdx.x & 63;
    const int wid = threadIdx.x >> 6;
    const int arow = m0 + wid * 16 + (lane & 15);
    const int kgrp = (lane >> 4) * 8;
    f32x4 acc[16];
#pragma unroll
    for (int i = 0; i < 16; ++i) acc[i] = (f32x4){0.f, 0.f, 0.f, 0.f};

    for (int k0 = 0; k0 < IN_F; k0 += 32) {
        const float* xp = x + (size_t)arow * IN_F + k0 + kgrp;
        float4 a0 = *(const float4*)xp, a1 = *(const float4*)(xp + 4);
        short8v af;
        af[0]=(short)f2bf(a0.x); af[1]=(short)f2bf(a0.y); af[2]=(short)f2bf(a0.z); af[3]=(short)f2bf(a0.w);
        af[4]=(short)f2bf(a1.x); af[5]=(short)f2bf(a1.y); af[6]=(short)f2bf(a1.z); af[7]=(short)f2bf(a1.w);
#pragma unroll
        for (int fc = 0; fc < 16; ++fc) {
            const float* wp = W1 + (size_t)(fc * 16 + (lane & 15)) * IN_F + k0 + kgrp;
            float4 b0 = *(const float4*)wp, b1v = *(const float4*)(wp + 4);
            short8v bf_;
            bf_[0]=(short)f2bf(b0.x); bf_[1]=(short)f2bf(b0.y); bf_[2]=(short)f2bf(b0.z); bf_[3]=(short)f2bf(b0.w);
            bf_[4]=(short)f2bf(b1v.x); bf_[5]=(short)f2bf(b1v.y); bf_[6]=(short)f2bf(b1v.z); bf_[7]=(short)f2bf(b1v.w);
            acc[fc] = __builtin_amdgcn_mfma_f32_16x16x32_bf16(af, bf_, acc[fc], 0, 0, 0);
        }
    }
#pragma unroll
    for (int fc = 0; fc < 16; ++fc) {
        const int col = fc * 16 + (lane & 15);
        const float bb = bias1[col];
#pragma unroll
        for (int rg = 0; rg < 4; ++rg) {
            const int orow = m0 + wid * 16 + (lane >> 4) * 4 + rg;
            h1[(size_t)orow * HID + col] = f2bf(acc[fc][rg] + bb);
        }
    }
}

// ---------------- K2b: hT[512,8192] (bf16) = W2 @ h1^T + b2 ----------------
__global__ __launch_bounds__(256) void k_fc2(const u16* __restrict__ h1,
                                             const float* __restrict__ W2,
                                             const float* __restrict__ bias2,
                                             u16* __restrict__ hT) {
    const int n0 = blockIdx.x * 64;   // node dim
    const int m0 = blockIdx.y * 64;   // out-feature dim
    const int lane = threadIdx.x & 63;
    const int wid = threadIdx.x >> 6;
    const int mrow = m0 + wid * 16 + (lane & 15);
    const int kgrp = (lane >> 4) * 8;
    f32x4 acc[4];
#pragma unroll
    for (int i = 0; i < 4; ++i) acc[i] = (f32x4){0.f, 0.f, 0.f, 0.f};

    for (int k0 = 0; k0 < HID; k0 += 32) {
        const float* wp = W2 + (size_t)mrow * HID + k0 + kgrp;
        float4 a0 = *(const float4*)wp, a1 = *(const float4*)(wp + 4);
        short8v af;
        af[0]=(short)f2bf(a0.x); af[1]=(short)f2bf(a0.y); af[2]=(short)f2bf(a0.z); af[3]=(short)f2bf(a0.w);
        af[4]=(short)f2bf(a1.x); af[5]=(short)f2bf(a1.y); af[6]=(short)f2bf(a1.z); af[7]=(short)f2bf(a1.w);
#pragma unroll
        for (int fc = 0; fc < 4; ++fc) {
            const u16* bp = h1 + (size_t)(n0 + fc * 16 + (lane & 15)) * HID + k0 + kgrp;
            short8v bf_ = *(const short8v*)bp;
            acc[fc] = __builtin_amdgcn_mfma_f32_16x16x32_bf16(af, bf_, acc[fc], 0, 0, 0);
        }
    }
#pragma unroll
    for (int fc = 0; fc < 4; ++fc) {
        const int n = n0 + fc * 16 + (lane & 15);
#pragma unroll
        for (int rg = 0; rg < 4; ++rg) {
            const int m = m0 + wid * 16 + (lane >> 4) * 4 + rg;
            hT[(size_t)m * N_NODES + n] = f2bf(acc[fc][rg] + bias2[m]);
        }
    }
}

// ---------------- K3: out[8192,512] (f32) = Anorm @ h ----------------
// BM=64, BN=256, BK=64. grid = 128 row-tiles * 2 col-tiles = 256 blocks, 512 thr (8 waves 2x4).
__global__ __launch_bounds__(512) void k_prop(const float* __restrict__ adj,
                                              const float* __restrict__ r,
                                              const u16* __restrict__ hT,
                                              float* __restrict__ out) {
    const int b = blockIdx.x;
    const int m0 = (b >> 1) * 64;
    const int n0 = (b & 1) * 256;
    const int tid = threadIdx.x;
    const int lane = tid & 63;
    const int wid = tid >> 6;
    const int wr = wid >> 2;          // 0..1
    const int wc = wid & 3;           // 0..3

    __shared__ u16 Alds[64 * 64];     // 8 KB, XOR-swizzled rows of 128B

    f32x4 acc[2][4];
#pragma unroll
    for (int i = 0; i < 2; ++i)
#pragma unroll
        for (int j = 0; j < 4; ++j) acc[i][j] = (f32x4){0.f, 0.f, 0.f, 0.f};

    const int srow = tid >> 3;        // 0..63
    const int sseg = tid & 7;         // 0..7
    const int grow = m0 + srow;
    const float ri = r[grow];
    const size_t arow_off = (size_t)grow * N_NODES;

    for (int k0 = 0; k0 < N_NODES; k0 += 64) {
        // ---- stage A tile: load f32, normalize, +I, cvt bf16 ----
        const float4* ap = (const float4*)(adj + arow_off + k0 + sseg * 8);
        float4 a0 = ap[0], a1 = ap[1];
        const float4* rp = (const float4*)(r + k0 + sseg * 8);
        float4 r0 = rp[0], r1 = rp[1];
        float va[8] = {a0.x, a0.y, a0.z, a0.w, a1.x, a1.y, a1.z, a1.w};
        float vr[8] = {r0.x, r0.y, r0.z, r0.w, r1.x, r1.y, r1.z, r1.w};
        const int gcol0 = k0 + sseg * 8;
        short8v pkv;
#pragma unroll
        for (int j = 0; j < 8; ++j) {
            float v = va[j];
            if (grow == gcol0 + j) v += 1.0f;       // + identity
            pkv[j] = (short)f2bf(v * ri * vr[j]);
        }
        __syncthreads();  // previous iter's reads done
        const int kb = (sseg * 16) ^ ((srow & 7) << 4);
        *(short8v*)((char*)Alds + srow * 128 + kb) = pkv;
        __syncthreads();

        // ---- compute: 2 x k32 steps ----
#pragma unroll
        for (int ks = 0; ks < 2; ++ks) {
            short8v afr[2];
#pragma unroll
            for (int fr = 0; fr < 2; ++fr) {
                const int row = wr * 32 + fr * 16 + (lane & 15);
                const int kbyte = (ks * 64 + 16 * (lane >> 4)) ^ ((row & 7) << 4);
                afr[fr] = *(const short8v*)((const char*)Alds + row * 128 + kbyte);
            }
            short8v bfr[4];
#pragma unroll
            for (int fc = 0; fc < 4; ++fc) {
                const int col = n0 + wc * 64 + fc * 16 + (lane & 15);
                bfr[fc] = *(const short8v*)(hT + (size_t)col * N_NODES + k0 + ks * 32 + 8 * (lane >> 4));
            }
#pragma unroll
            for (int fr = 0; fr < 2; ++fr)
#pragma unroll
                for (int fc = 0; fc < 4; ++fc)
                    acc[fr][fc] = __builtin_amdgcn_mfma_f32_16x16x32_bf16(afr[fr], bfr[fc], acc[fr][fc], 0, 0, 0);
        }
    }

    // ---- epilogue: f32 store ----
#pragma unroll
    for (int fr = 0; fr < 2; ++fr)
#pragma unroll
        for (int fc = 0; fc < 4; ++fc) {
            const int col = n0 + wc * 64 + fc * 16 + (lane & 15);
#pragma unroll
            for (int rg = 0; rg < 4; ++rg) {
                const int row = m0 + wr * 32 + fr * 16 + (lane >> 4) * 4 + rg;
                out[(size_t)row * OUT_F + col] = acc[fr][fc][rg];
            }
        }
}

extern "C" void kernel_launch(void* const* d_in, const int* in_sizes, int n_in,
                              void* d_out, int out_size, void* d_ws, size_t ws_size,
                              hipStream_t stream) {
    const float* x    = (const float*)d_in[0];
    const float* adj  = (const float*)d_in[1];
    const float* W1   = (const float*)d_in[2];
    const float* b1   = (const float*)d_in[3];
    const float* W2   = (const float*)d_in[4];
    const float* b2   = (const float*)d_in[5];
    float* out = (float*)d_out;

    char* ws = (char*)d_ws;
    float* r  = (float*)ws;                                   // 32 KB
    u16* h1   = (u16*)(ws + 64 * 1024);                       // 4 MB
    u16* hT   = (u16*)(ws + 64 * 1024 + 4 * 1024 * 1024);     // 8 MB

    k_rowsum<<<N_NODES, 256, 0, stream>>>(adj, r);
    k_fc1<<<N_NODES / 64, 256, 0, stream>>>(x, W1, b1, h1);
    k_fc2<<<dim3(N_NODES / 64, OUT_F / 64), 256, 0, stream>>>(h1, W2, b2, hT);
    k_prop<<<256, 512, 0, stream>>>(adj, r, hT, out);
}

// Round 2
// 630.901 us; speedup vs baseline: 1.3716x; 1.3716x over previous
//
#include <hip/hip_runtime.h>
#include <hip/hip_bf16.h>

typedef unsigned short u16;
typedef __attribute__((ext_vector_type(8))) short short8v;
typedef __attribute__((ext_vector_type(4))) float f32x4;

#define N_NODES 8192
#define IN_F    512
#define HID     256
#define OUT_F   512

static __device__ __forceinline__ u16 f2bf(float f) {
    union { float f; unsigned u; } v; v.f = f;
    unsigned u = v.u;
    unsigned r = (u + 0x7FFFu + ((u >> 16) & 1u)) >> 16;  // RNE
    return (u16)r;
}

// ---------------- K1: rowsum(adj + I) -> r = rsqrt ----------------
__global__ __launch_bounds__(256) void k_rowsum(const float* __restrict__ adj,
                                                float* __restrict__ r) {
    const int row = blockIdx.x;
    const float* p = adj + (size_t)row * N_NODES;
    const int t = threadIdx.x;
    float s = 0.f;
#pragma unroll
    for (int it = 0; it < 8; ++it) {
        float4 v = *(const float4*)(p + it * 1024 + t * 4);
        s += (v.x + v.y) + (v.z + v.w);
    }
#pragma unroll
    for (int off = 32; off > 0; off >>= 1) s += __shfl_down(s, off, 64);
    __shared__ float red[4];
    const int lane = t & 63, wid = t >> 6;
    if (lane == 0) red[wid] = s;
    __syncthreads();
    if (t == 0) {
        float tot = red[0] + red[1] + red[2] + red[3] + 1.0f;  // +1 from identity
        r[row] = (tot > 0.f) ? rsqrtf(tot) : 0.f;
    }
}

// ---------------- K2: Wc = W2 @ W1 (f32 acc -> bf16), bc = W2@b1 + b2 ----------------
__global__ __launch_bounds__(256) void k_wc(const float* __restrict__ W1,
                                            const float* __restrict__ b1,
                                            const float* __restrict__ W2,
                                            const float* __restrict__ b2,
                                            u16* __restrict__ Wcb,
                                            float* __restrict__ bc) {
    const int o0 = blockIdx.x * 8;
    __shared__ float w2s[8][256];   // 8 KB
    const int tid = threadIdx.x;
    for (int idx = tid; idx < 8 * 256; idx += 256) {
        int o = idx >> 8, h = idx & 255;
        w2s[o][h] = W2[(size_t)(o0 + o) * HID + h];
    }
    __syncthreads();
    float acc[8][2];
#pragma unroll
    for (int o = 0; o < 8; ++o) { acc[o][0] = 0.f; acc[o][1] = 0.f; }
#pragma unroll 4
    for (int h = 0; h < 256; ++h) {
        float a = W1[(size_t)h * IN_F + tid];
        float b = W1[(size_t)h * IN_F + tid + 256];
#pragma unroll
        for (int o = 0; o < 8; ++o) {
            float w = w2s[o][h];
            acc[o][0] += w * a;
            acc[o][1] += w * b;
        }
    }
#pragma unroll
    for (int o = 0; o < 8; ++o) {
        Wcb[(size_t)(o0 + o) * IN_F + tid]       = f2bf(acc[o][0]);
        Wcb[(size_t)(o0 + o) * IN_F + tid + 256] = f2bf(acc[o][1]);
    }
    if (tid < 8) {
        float s = b2[o0 + tid];
        for (int h = 0; h < 256; ++h) s += w2s[tid][h] * b1[h];
        bc[o0 + tid] = s;
    }
}

// ---------------- K3: hT[512][8192] bf16 = r_j * (x @ Wc^T + bc) transposed ----------------
__global__ __launch_bounds__(256) void k_h(const float* __restrict__ x,
                                           const u16* __restrict__ Wcb,
                                           const float* __restrict__ bc,
                                           const float* __restrict__ r,
                                           u16* __restrict__ hT) {
    const int j0 = blockIdx.x * 256;   // node block (32)
    const int f0 = blockIdx.y * 64;    // feature block (8)
    const int lane = threadIdx.x & 63;
    const int wid = threadIdx.x >> 6;  // 0..3
    const int jw = j0 + wid * 64;
    const int l16 = lane & 15;
    const int lk8 = (lane >> 4) * 8;

    f32x4 acc[4][4];
#pragma unroll
    for (int i = 0; i < 4; ++i)
#pragma unroll
        for (int j = 0; j < 4; ++j) acc[i][j] = (f32x4){0.f, 0.f, 0.f, 0.f};

    for (int k0 = 0; k0 < IN_F; k0 += 32) {
        short8v af[4];
#pragma unroll
        for (int fr = 0; fr < 4; ++fr)
            af[fr] = *(const short8v*)(Wcb + (size_t)(f0 + fr * 16 + l16) * IN_F + k0 + lk8);
        short8v bf_[4];
#pragma unroll
        for (int fc = 0; fc < 4; ++fc) {
            const float* xp = x + (size_t)(jw + fc * 16 + l16) * IN_F + k0 + lk8;
            float4 x0 = *(const float4*)xp, x1 = *(const float4*)(xp + 4);
            short8v t;
            t[0]=(short)f2bf(x0.x); t[1]=(short)f2bf(x0.y); t[2]=(short)f2bf(x0.z); t[3]=(short)f2bf(x0.w);
            t[4]=(short)f2bf(x1.x); t[5]=(short)f2bf(x1.y); t[6]=(short)f2bf(x1.z); t[7]=(short)f2bf(x1.w);
            bf_[fc] = t;
        }
#pragma unroll
        for (int fr = 0; fr < 4; ++fr)
#pragma unroll
            for (int fc = 0; fc < 4; ++fc)
                acc[fr][fc] = __builtin_amdgcn_mfma_f32_16x16x32_bf16(af[fr], bf_[fc], acc[fr][fc], 0, 0, 0);
    }
#pragma unroll
    for (int fc = 0; fc < 4; ++fc) {
        const int j = jw + fc * 16 + l16;
        const float rj = r[j];
#pragma unroll
        for (int fr = 0; fr < 4; ++fr) {
            const int fb = f0 + fr * 16 + (lane >> 4) * 4;
#pragma unroll
            for (int rg = 0; rg < 4; ++rg) {
                const int f = fb + rg;
                hT[(size_t)f * N_NODES + j] = f2bf(rj * (acc[fr][fc][rg] + bc[f]));
            }
        }
    }
}

// ---------------- K4: out = diag(r) (adj + I) hT^T ----------------
// BM=64, BN=128, BK=64. grid 512 (XCD-chunked), 256 thr (4 waves, 1x4 over cols).
static __device__ __forceinline__ void diag_fix(float4& v, int row, int seg) {
    const int d = row - seg * 4;
    if (d == 0) v.x += 1.0f;
    else if (d == 1) v.y += 1.0f;
    else if (d == 2) v.z += 1.0f;
    else if (d == 3) v.w += 1.0f;
}

static __device__ __forceinline__ void st_row(u16* lds, float4 v, int row, int seg) {
    ushort4 p;
    p.x = f2bf(v.x); p.y = f2bf(v.y); p.z = f2bf(v.z); p.w = f2bf(v.w);
    *(ushort4*)((char*)lds + ((row * 128 + seg * 8) ^ ((row & 7) << 4))) = p;
}

__global__ __launch_bounds__(256, 2) void k_prop(const float* __restrict__ adj,
                                                 const float* __restrict__ r,
                                                 const u16* __restrict__ hT,
                                                 float* __restrict__ out) {
    const int bid = blockIdx.x;
    // XCD-aware mapping: xcd = bid&7 owns col group (bid&3) and row half ((bid>>2)&1).
    const int n0 = (bid & 3) * 128;
    const int m0 = (((bid >> 2) & 1) * 64 + (bid >> 3)) * 64;
    const int tid = threadIdx.x;
    const int lane = tid & 63;
    const int wid = tid >> 6;          // 0..3 : 32-col group

    __shared__ u16 Alds[64 * 64];      // 8 KB, XOR-swizzled

    f32x4 acc[4][2];
#pragma unroll
    for (int i = 0; i < 4; ++i) { acc[i][0] = (f32x4){0,0,0,0}; acc[i][1] = (f32x4){0,0,0,0}; }

    // A staging: thread covers rows s_row+{0,16,32,48}, float4 seg s_seg
    const int s_row = tid >> 4;        // 0..15
    const int s_seg = tid & 15;        // 0..15
    const float* aptr = adj + (size_t)(m0 + s_row) * N_NODES + s_seg * 4;

    // B pointers (hT rows = output features)
    const int l16 = lane & 15;
    const int lk8 = (lane >> 4) * 8;
    const u16* hp0 = hT + (size_t)(n0 + wid * 32 + l16) * N_NODES + lk8;
    const u16* hp1 = hp0 + (size_t)16 * N_NODES;

    // A-fragment LDS byte offsets (fr, ks) with matching swizzle
    int aoff[4][2];
#pragma unroll
    for (int fr = 0; fr < 4; ++fr) {
        const int arow = fr * 16 + l16;
        const int sw = (arow & 7) << 4;
#pragma unroll
        for (int ks = 0; ks < 2; ++ks)
            aoff[fr][ks] = arow * 128 + ((ks * 64 + (lane >> 4) * 16) ^ sw);
    }

#define LOADA(k0, P) do { \
    const float* ap_ = aptr + (k0); \
    P##0 = *(const float4*)ap_; \
    P##1 = *(const float4*)(ap_ + 16 * (size_t)N_NODES); \
    P##2 = *(const float4*)(ap_ + 32 * (size_t)N_NODES); \
    P##3 = *(const float4*)(ap_ + 48 * (size_t)N_NODES); \
} while (0)

#define LOADB(k0, P) do { \
    P##00 = *(const short8v*)(hp0 + (k0)); \
    P##01 = *(const short8v*)(hp0 + (k0) + 32); \
    P##10 = *(const short8v*)(hp1 + (k0)); \
    P##11 = *(const short8v*)(hp1 + (k0) + 32); \
} while (0)

#define STOREA(k0, P) do { \
    float4 v0_ = P##0, v1_ = P##1, v2_ = P##2, v3_ = P##3; \
    if ((k0) == m0) { \
        diag_fix(v0_, s_row, s_seg);      diag_fix(v1_, s_row + 16, s_seg); \
        diag_fix(v2_, s_row + 32, s_seg); diag_fix(v3_, s_row + 48, s_seg); \
    } \
    st_row(Alds, v0_, s_row, s_seg);      st_row(Alds, v1_, s_row + 16, s_seg); \
    st_row(Alds, v2_, s_row + 32, s_seg); st_row(Alds, v3_, s_row + 48, s_seg); \
} while (0)

#define COMPUTE(P) do { \
    short8v a_[4][2]; \
    _Pragma("unroll") \
    for (int fr_ = 0; fr_ < 4; ++fr_) { \
        a_[fr_][0] = *(const short8v*)((const char*)Alds + aoff[fr_][0]); \
        a_[fr_][1] = *(const short8v*)((const char*)Alds + aoff[fr_][1]); \
    } \
    _Pragma("unroll") \
    for (int fr_ = 0; fr_ < 4; ++fr_) { \
        acc[fr_][0] = __builtin_amdgcn_mfma_f32_16x16x32_bf16(a_[fr_][0], P##00, acc[fr_][0], 0, 0, 0); \
        acc[fr_][1] = __builtin_amdgcn_mfma_f32_16x16x32_bf16(a_[fr_][0], P##10, acc[fr_][1], 0, 0, 0); \
        acc[fr_][0] = __builtin_amdgcn_mfma_f32_16x16x32_bf16(a_[fr_][1], P##01, acc[fr_][0], 0, 0, 0); \
        acc[fr_][1] = __builtin_amdgcn_mfma_f32_16x16x32_bf16(a_[fr_][1], P##11, acc[fr_][1], 0, 0, 0); \
    } \
} while (0)

    float4 Ae0, Ae1, Ae2, Ae3, Ao0, Ao1, Ao2, Ao3;
    short8v Be00, Be01, Be10, Be11, Bo00, Bo01, Bo10, Bo11;

    LOADA(0, Ae);
    LOADB(0, Be);

    for (int k0 = 0; k0 < N_NODES; k0 += 128) {
        STOREA(k0, Ae);
        asm volatile("s_waitcnt lgkmcnt(0)" ::: "memory");
        __builtin_amdgcn_s_barrier();
        LOADA(k0 + 64, Ao);          // prefetch next tile (stays in flight across barriers)
        LOADB(k0 + 64, Bo);
        COMPUTE(Be);
        __builtin_amdgcn_s_barrier();

        STOREA(k0 + 64, Ao);
        asm volatile("s_waitcnt lgkmcnt(0)" ::: "memory");
        __builtin_amdgcn_s_barrier();
        if (k0 + 128 < N_NODES) {
            LOADA(k0 + 128, Ae);
            LOADB(k0 + 128, Be);
        }
        COMPUTE(Bo);
        __builtin_amdgcn_s_barrier();
    }

    // epilogue: out = r_i * acc
#pragma unroll
    for (int fr = 0; fr < 4; ++fr) {
        const int rbase = m0 + fr * 16 + (lane >> 4) * 4;
        float4 rv = *(const float4*)(r + rbase);
#pragma unroll
        for (int rg = 0; rg < 4; ++rg) {
            const float rs = ((const float*)&rv)[rg];
            const size_t o = (size_t)(rbase + rg) * OUT_F + n0 + wid * 32 + l16;
            out[o]      = rs * acc[fr][0][rg];
            out[o + 16] = rs * acc[fr][1][rg];
        }
    }
#undef LOADA
#undef LOADB
#undef STOREA
#undef COMPUTE
}

extern "C" void kernel_launch(void* const* d_in, const int* in_sizes, int n_in,
                              void* d_out, int out_size, void* d_ws, size_t ws_size,
                              hipStream_t stream) {
    const float* x   = (const float*)d_in[0];
    const float* adj = (const float*)d_in[1];
    const float* W1  = (const float*)d_in[2];
    const float* b1  = (const float*)d_in[3];
    const float* W2  = (const float*)d_in[4];
    const float* b2  = (const float*)d_in[5];
    float* out = (float*)d_out;

    char* ws = (char*)d_ws;
    float* r   = (float*)ws;                    // 32 KB   @ 0
    float* bc  = (float*)(ws + 32 * 1024);      // 2 KB    @ 32K
    u16*   Wcb = (u16*)(ws + 64 * 1024);        // 512 KB  @ 64K
    u16*   hT  = (u16*)(ws + 1024 * 1024);      // 8 MB    @ 1M

    k_rowsum<<<N_NODES, 256, 0, stream>>>(adj, r);
    k_wc<<<64, 256, 0, stream>>>(W1, b1, W2, b2, Wcb, bc);
    k_h<<<dim3(32, 8), 256, 0, stream>>>(x, Wcb, bc, r, hT);
    k_prop<<<512, 256, 0, stream>>>(adj, r, hT, out);
}